// Round 6
// baseline (360.173 us; speedup 1.0000x reference)
//
#include <hip/hip_runtime.h>

#define B_ 128
#define T_ 2048
#define N_ 64
#define L_ 256
#define NEGV (-1e30f)
#define PITCH 72   // shorts per LDS row (64 + 8 pad), 144 B -> keeps b128 16B-aligned
#define LOG2E 1.4426950408889634f
#define LN2   0.6931471805599453f

typedef short  s16x4 __attribute__((ext_vector_type(4)));
typedef short  s16x8 __attribute__((ext_vector_type(8)));
typedef float  f32x4 __attribute__((ext_vector_type(4)));
typedef unsigned int u32x2 __attribute__((ext_vector_type(2)));

__device__ __forceinline__ short f2bf_rne(float f) {
    unsigned u = __float_as_uint(f);
    unsigned r = (u + 0x7FFFu + ((u >> 16) & 1u)) >> 16;
    return (short)r;
}
__device__ __forceinline__ float bf2f(unsigned short u) {
    return __uint_as_float(((unsigned)u) << 16);
}
// pack 2 floats -> 2 bf16 (round-half-up) in one u32 via v_perm_b32
__device__ __forceinline__ unsigned pkpair(float lo, float hi) {
    return __builtin_amdgcn_perm(__float_as_uint(hi) + 0x8000u,
                                 __float_as_uint(lo) + 0x8000u, 0x07060302u);
}
__device__ __forceinline__ float bperm(int byteaddr, float v) {
    return __int_as_float(__builtin_amdgcn_ds_bpermute(byteaddr, __float_as_int(v)));
}
// logaddexp in log2 domain (v_exp_f32/v_log_f32 are base-2)
__device__ __forceinline__ float lse2b(float p, float q) {
    float mx = fmaxf(p, q);
    float t  = __builtin_amdgcn_exp2f(-fabsf(p - q));
    return mx + __builtin_amdgcn_logf(1.f + t);
}

// Kernel 1: blocks 0..255 wave0 = fac (fwd b=blk / bwd b=blk-128), 1 fac wave per CU;
// all other waves = fcc chunk transfer-matrix builders.
__global__ __launch_bounds__(256, 2) void asg_k1(
    const float* __restrict__ x,       // (B,T,N)
    const int*   __restrict__ target,  // (B,L)
    const int*   __restrict__ tsize,   // (B,)
    const float* __restrict__ trans,   // (N,N)
    float* __restrict__ ws_c,          // (B,32) chunk log-scales
    unsigned short* __restrict__ ws_R, // (B,32,64,64) bf16 chunk matrices [m][n]
    float* __restrict__ ws_v,          // (B,256) alpha_1023 (log2 domain)
    float* __restrict__ ws_w)          // (B,256) beta_1023  (log2 domain)
{
    __shared__ short lds[4][N_ * PITCH];
    const int blk  = blockIdx.x;
    const int wid  = threadIdx.x >> 6;
    const int lane = threadIdx.x & 63;
    const bool isfac = (blk < 256) && (wid == 0);

    if (isfac && blk < 128) {
        // ---------------- FAC forward: alpha_0 .. alpha_1023 ----------------
        const int b  = blk;
        const float* __restrict__ xb = x + (size_t)b * T_ * N_;
        const int l0 = lane * 4;
        int tga[4]; float slf[4], mv[4], a[4];
        #pragma unroll
        for (int j = 0; j < 4; ++j) {
            const int tv = target[b * L_ + l0 + j];
            tga[j] = tv << 2;
            slf[j] = trans[tv * N_ + tv] * LOG2E;
            if (j > 0) mv[j] = trans[tv * N_ + (target[b * L_ + l0 + j - 1])] * LOG2E;
            a[j] = NEGV;
        }
        const int tR  = target[b * L_ + ((l0 - 1 >= 0) ? l0 - 1 : 0)];
        const int tR1 = target[b * L_ + ((l0 - 2 >= 0) ? l0 - 2 : 0)];
        const int tgR = tR << 2;
        const float slfR = trans[tR * N_ + tR] * LOG2E;
        const float mvR  = trans[tR * N_ + tR1] * LOG2E;
        mv[0] = trans[(tga[0] >> 2) * N_ + tR] * LOG2E;
        if (lane == 0) a[0] = xb[tga[0] >> 2] * LOG2E;   // alpha0[0]
        float red = NEGV;
        const int upA = ((lane == 0) ? 0 : lane - 1) << 2;

        float xr[16];
        #pragma unroll
        for (int i = 0; i < 16; ++i) xr[i] = xb[(size_t)(1 + i) * N_ + lane];
        float sc = xr[0] * LOG2E;
        float eR = bperm(tgR, sc);
        float e0 = bperm(tga[0], sc), e1 = bperm(tga[1], sc),
              e2 = bperm(tga[2], sc), e3 = bperm(tga[3], sc);
        float bp = bperm(upA, a[2]);

        #define FWD_STEP(i, rp, RF)                                             \
        {                                                                       \
            const float ceR = eR, c0 = e0, c1 = e1, c2 = e2, c3 = e3;           \
            float scn = xr[((i) + 1) & 15] * LOG2E;                             \
            eR = bperm(tgR, scn);                                               \
            e0 = bperm(tga[0], scn); e1 = bperm(tga[1], scn);                   \
            e2 = bperm(tga[2], scn); e3 = bperm(tga[3], scn);                   \
            if (RF) xr[i] = (rp)[lane];                                         \
            const float n0 = lse2b(a[0] + slf[0], red  + mv[0]) + c0;           \
            const float n1 = lse2b(a[1] + slf[1], a[0] + mv[1]) + c1;           \
            const float n2 = lse2b(a[2] + slf[2], a[1] + mv[2]) + c2;           \
            const float n3 = lse2b(a[3] + slf[3], a[2] + mv[3]) + c3;           \
            const float nr = lse2b(red + slfR,    bp   + mvR)   + ceR;          \
            bp = bperm(upA, n2);                                                \
            a[0] = n0; a[1] = n1; a[2] = n2; a[3] = n3;                         \
            red = (lane == 0) ? NEGV : nr;                                      \
        }
        for (int u = 0; u < 63; ++u) {                  // t = 1..1008
            const float* __restrict__ xp = xb + (size_t)(16 * u + 17) * N_;
            #pragma unroll
            for (int i = 0; i < 16; ++i) FWD_STEP(i, xp + i * N_, true);
        }
        #pragma unroll
        for (int i = 0; i < 15; ++i) FWD_STEP(i, xb, false);   // t = 1009..1023
        #undef FWD_STEP
        *(float4*)(ws_v + b * 256 + l0) = make_float4(a[0], a[1], a[2], a[3]);
    } else if (isfac) {
        // ---------------- FAC backward: beta_2047 .. beta_1023 ----------------
        const int b  = blk - 128;
        const float* __restrict__ xb = x + (size_t)b * T_ * N_;
        const int l0 = lane * 4;
        const int lt = tsize[b] - 1;
        int tga[4]; float slf[4], mvin[4], a[4];
        #pragma unroll
        for (int j = 0; j < 4; ++j) {
            const int tv = target[b * L_ + l0 + j];
            tga[j] = tv << 2;
            slf[j] = trans[tv * N_ + tv] * LOG2E;
            if (j > 0) mvin[j] = trans[tv * N_ + (target[b * L_ + l0 + j - 1])] * LOG2E;
            a[j] = (l0 + j == lt) ? 0.f : NEGV;
        }
        const int tR  = target[b * L_ + ((l0 + 4 <= L_ - 1) ? l0 + 4 : L_ - 1)];
        const int tR2 = target[b * L_ + ((l0 + 5 <= L_ - 1) ? l0 + 5 : L_ - 1)];
        const int tgR = tR << 2, tgR2 = tR2 << 2;
        const float slfR = trans[tR * N_ + tR] * LOG2E;
        const float mvR  = trans[tR * N_ + (tga[3] >> 2)] * LOG2E;  // move into 4m+4
        const float mvR2 = trans[tR2 * N_ + tR] * LOG2E;            // move into 4m+5
        float red = (l0 + 4 == lt) ? 0.f : NEGV;
        const int dnA = ((lane == 63) ? 63 : lane + 1) << 2;

        float xr[16];
        #pragma unroll
        for (int i = 0; i < 16; ++i) xr[i] = xb[(size_t)(2047 - i) * N_ + lane];
        float sc = xr[0] * LOG2E;
        float eR = bperm(tgR, sc), eR2 = bperm(tgR2, sc);
        float e0 = bperm(tga[0], sc), e1 = bperm(tga[1], sc),
              e2 = bperm(tga[2], sc), e3 = bperm(tga[3], sc);
        float bp = bperm(dnA, a[1]);

        #define BWD_STEP(i, rp, RF)                                             \
        {                                                                       \
            const float ceR = eR, ceR2 = eR2, c0 = e0, c1 = e1, c2 = e2, c3 = e3;\
            float scn = xr[((i) + 1) & 15] * LOG2E;                             \
            eR = bperm(tgR, scn); eR2 = bperm(tgR2, scn);                       \
            e0 = bperm(tga[0], scn); e1 = bperm(tga[1], scn);                   \
            e2 = bperm(tga[2], scn); e3 = bperm(tga[3], scn);                   \
            if (RF) xr[i] = (rp)[lane];                                         \
            const float t0 = a[0] + c0, t1 = a[1] + c1, t2 = a[2] + c2,         \
                        t3 = a[3] + c3, tr = red + ceR;                         \
            const float n0 = lse2b(t0 + slf[0], t1 + mvin[1]);                  \
            const float n1 = lse2b(t1 + slf[1], t2 + mvin[2]);                  \
            const float n2 = lse2b(t2 + slf[2], t3 + mvin[3]);                  \
            const float n3 = lse2b(t3 + slf[3], tr + mvR);                      \
            const float nr = lse2b(tr + slfR, bp + ceR2 + mvR2);                \
            bp = bperm(dnA, n1);                                                \
            a[0] = n0; a[1] = n1; a[2] = n2; a[3] = n3;                         \
            red = (lane == 63) ? NEGV : nr;                                     \
        }
        for (int u = 0; u < 63; ++u) {                  // t = 2047..1040
            const float* __restrict__ xp = xb + (size_t)(2047 - 16 * u - 16) * N_;
            #pragma unroll
            for (int i = 0; i < 16; ++i) BWD_STEP(i, xp - (size_t)i * N_, true);
        }
        #pragma unroll
        for (int i = 0; i < 16; ++i) BWD_STEP(i, xb, false);   // t = 1039..1024
        #undef BWD_STEP
        *(float4*)(ws_w + b * 256 + l0) = make_float4(a[0], a[1], a[2], a[3]);
    } else {
        // ---------------- FCC chunk: P = prod_s D_t*Ehat over 64 steps --------
        const int task = (blk < 256) ? (blk * 3 + (wid - 1))
                                     : (768 + (blk - 256) * 4 + wid);
        const int b = task >> 5, k = task & 31;
        const int c = lane & 15, g = lane >> 4;
        const float* __restrict__ xb = x + (size_t)b * T_ * N_;
        const int t0 = k * 64;
        short* __restrict__ myl = lds[wid];

        s16x8 Afrag[4][2];
        float rs[4] = {0.f, 0.f, 0.f, 0.f};
        #pragma unroll
        for (int mt = 0; mt < 4; ++mt)
            #pragma unroll
            for (int kt = 0; kt < 2; ++kt) {
                s16x8 af;
                #pragma unroll
                for (int jj = 0; jj < 8; ++jj) {
                    float v = __expf(trans[(c + 16 * mt) * N_ + 32 * kt + 8 * g + jj]);
                    af[jj] = f2bf_rne(v);
                    rs[mt] += v;
                }
                Afrag[mt][kt] = af;
            }
        #pragma unroll
        for (int mt = 0; mt < 4; ++mt) {
            rs[mt] += __shfl_xor(rs[mt], 16);
            rs[mt] += __shfl_xor(rs[mt], 32);
        }
        float rmax = fmaxf(fmaxf(rs[0], rs[1]), fmaxf(rs[2], rs[3]));
        #pragma unroll
        for (int o = 8; o > 0; o >>= 1) rmax = fmaxf(rmax, __shfl_xor(rmax, o));
        const float LS = __logf(rmax);

        s16x8 Bfrag[2][4];
        #pragma unroll
        for (int kt = 0; kt < 2; ++kt)
            #pragma unroll
            for (int nt = 0; nt < 4; ++nt) {
                s16x8 bf;
                #pragma unroll
                for (int jj = 0; jj < 8; ++jj)
                    bf[jj] = (32 * kt + 8 * g + jj == c + 16 * nt) ? (short)0x3F80 : (short)0;
                Bfrag[kt][nt] = bf;
            }

        float4 xr[2][4];
        #pragma unroll
        for (int p = 0; p < 2; ++p)
            #pragma unroll
            for (int tr = 0; tr < 4; ++tr)
                xr[p][tr] = *(const float4*)(xb + (size_t)(t0 + 1 + p) * N_ + 16 * tr + 4 * g);

        float c_acc = 0.f;
        #pragma unroll 2
        for (int s = 0; s < 64; ++s) {
            const int t = t0 + 1 + s;
            f32x4 Cacc[4][4];
            #pragma unroll
            for (int mt = 0; mt < 4; ++mt)
                #pragma unroll
                for (int nt = 0; nt < 4; ++nt) {
                    f32x4 z = {0.f, 0.f, 0.f, 0.f};
                    z = __builtin_amdgcn_mfma_f32_16x16x32_bf16(Afrag[mt][0], Bfrag[0][nt], z, 0, 0, 0);
                    Cacc[mt][nt] = __builtin_amdgcn_mfma_f32_16x16x32_bf16(Afrag[mt][1], Bfrag[1][nt], z, 0, 0, 0);
                }
            float4 xv[4];
            #pragma unroll
            for (int tr = 0; tr < 4; ++tr) xv[tr] = xr[s & 1][tr];
            int tpre = t + 2; if (tpre > T_ - 1) tpre = T_ - 1;
            #pragma unroll
            for (int tr = 0; tr < 4; ++tr)
                xr[s & 1][tr] = *(const float4*)(xb + (size_t)tpre * N_ + 16 * tr + 4 * g);

            const float gt = __uint_as_float(__builtin_amdgcn_readfirstlane(__float_as_uint(xv[0].x))) + LS;
            if (t < T_) {
                c_acc += gt;
                float ev[4][4];
                #pragma unroll
                for (int tr = 0; tr < 4; ++tr) {
                    ev[tr][0] = __expf(xv[tr].x - gt);
                    ev[tr][1] = __expf(xv[tr].y - gt);
                    ev[tr][2] = __expf(xv[tr].z - gt);
                    ev[tr][3] = __expf(xv[tr].w - gt);
                }
                #pragma unroll
                for (int mt = 0; mt < 4; ++mt)
                    #pragma unroll
                    for (int nt = 0; nt < 4; ++nt) {
                        u32x2 pk;
                        pk[0] = pkpair(Cacc[mt][nt][0] * ev[mt][0], Cacc[mt][nt][1] * ev[mt][1]);
                        pk[1] = pkpair(Cacc[mt][nt][2] * ev[mt][2], Cacc[mt][nt][3] * ev[mt][3]);
                        *(u32x2*)&myl[(16 * nt + c) * PITCH + 16 * mt + 4 * g] = pk;
                    }
                #pragma unroll
                for (int kt = 0; kt < 2; ++kt)
                    #pragma unroll
                    for (int nt = 0; nt < 4; ++nt)
                        Bfrag[kt][nt] = *(const s16x8*)&myl[(16 * nt + c) * PITCH + 32 * kt + 8 * g];
            }
        }
        unsigned short* dst = ws_R + (size_t)(b * 32 + k) * 4096;
        #pragma unroll
        for (int r = 0; r < 8; ++r) {
            s16x8 v = *(const s16x8*)&myl[lane * PITCH + r * 8];  // v[e] = P[8r+e][lane]
            #pragma unroll
            for (int e = 0; e < 8; ++e)
                dst[(8 * r + e) * 64 + lane] = (unsigned short)v[e];
        }
        if (lane == 0) ws_c[b * 32 + k] = c_acc;
    }
}

// Kernel 2: wave0 = fcc chunk combine (LDS-staged, 2-deep prefetch, cheap renorm);
//           wave1 = fwd/bwd fac combine. One block per batch.
__global__ __launch_bounds__(128) void asg_k2(
    const float* __restrict__ x,
    const float* __restrict__ ws_c,
    const unsigned short* __restrict__ ws_R,
    const float* __restrict__ ws_v,
    const float* __restrict__ ws_w,
    float* __restrict__ out)
{
    __shared__ short rb[2][N_ * PITCH];
    __shared__ __align__(16) float sa[N_];
    __shared__ float sres[2];
    const int b = blockIdx.x, tid = threadIdx.x, lane = tid & 63;

    if (tid < 64) {
        float a0 = x[(size_t)b * T_ * N_ + lane];
        float m0 = a0;
        #pragma unroll
        for (int o = 32; o > 0; o >>= 1) m0 = fmaxf(m0, __shfl_xor(m0, o));
        float  a  = __expf(a0 - m0);
        double Cd = (double)m0;

        const unsigned short* Rb = ws_R + (size_t)b * 32 * 4096;
        const int frow = (lane >> 3), fcol = (lane & 7) * 8;  // staging lane slot
        // preload chunk 0 -> LDS buf 0 (coalesced b128)
        #pragma unroll
        for (int q = 0; q < 8; ++q) {
            s16x8 v = *(const s16x8*)(Rb + lane * 8 + 512 * q);
            *(s16x8*)&rb[0][(frow + 8 * q) * PITCH + fcol] = v;
        }
        // preload chunk 1 -> regs
        s16x8 nv[8];
        #pragma unroll
        for (int q = 0; q < 8; ++q)
            nv[q] = *(const s16x8*)(Rb + 4096 + lane * 8 + 512 * q);

        for (int kk = 0; kk < 32; ++kk) {
            // broadcast a, dot with chunk kk from LDS
            sa[lane] = a;
            float4 sav[16];
            #pragma unroll
            for (int q = 0; q < 16; ++q) sav[q] = ((const float4*)sa)[q];

            float acc4[4] = {0.f, 0.f, 0.f, 0.f};
            #pragma unroll
            for (int u = 0; u < 8; ++u) {
                s16x8 rr = *(const s16x8*)&rb[kk & 1][lane * PITCH + u * 8];
                const float4 s0 = sav[2 * u], s1 = sav[2 * u + 1];
                acc4[0] = fmaf(bf2f((unsigned short)rr[0]), s0.x, acc4[0]);
                acc4[1] = fmaf(bf2f((unsigned short)rr[1]), s0.y, acc4[1]);
                acc4[2] = fmaf(bf2f((unsigned short)rr[2]), s0.z, acc4[2]);
                acc4[3] = fmaf(bf2f((unsigned short)rr[3]), s0.w, acc4[3]);
                acc4[0] = fmaf(bf2f((unsigned short)rr[4]), s1.x, acc4[0]);
                acc4[1] = fmaf(bf2f((unsigned short)rr[5]), s1.y, acc4[1]);
                acc4[2] = fmaf(bf2f((unsigned short)rr[6]), s1.z, acc4[2]);
                acc4[3] = fmaf(bf2f((unsigned short)rr[7]), s1.w, acc4[3]);
            }
            float acc = (acc4[0] + acc4[1]) + (acc4[2] + acc4[3]);

            // stage chunk kk+1 (regs) -> LDS, then prefetch chunk kk+2 -> regs
            #pragma unroll
            for (int q = 0; q < 8; ++q)
                *(s16x8*)&rb[(kk + 1) & 1][(frow + 8 * q) * PITCH + fcol] = nv[q];
            const int kp = (kk + 2 < 32) ? kk + 2 : 31;
            #pragma unroll
            for (int q = 0; q < 8; ++q)
                nv[q] = *(const s16x8*)(Rb + (size_t)kp * 4096 + lane * 8 + 512 * q);

            // cheap renorm: all-positive acc, lane0's value is within e^+-10 of max
            float r = bperm(0, acc);
            a = acc * __builtin_amdgcn_rcpf(r);
            Cd += (double)(__logf(r) + ws_c[b * 32 + kk]);
        }
        float ssum = a;
        #pragma unroll
        for (int o = 32; o > 0; o >>= 1) ssum += __shfl_xor(ssum, o);
        if (lane == 0) sres[0] = (float)(Cd + (double)__logf(ssum));
    } else {
        // fac combine: F = ln-domain lse over 256 cells of (alpha+beta), log2 inputs
        float4 v4 = ((const float4*)(ws_v + b * 256))[lane];
        float4 w4 = ((const float4*)(ws_w + b * 256))[lane];
        const float s0 = v4.x + w4.x, s1 = v4.y + w4.y,
                    s2 = v4.z + w4.z, s3 = v4.w + w4.w;
        float m = fmaxf(fmaxf(s0, s1), fmaxf(s2, s3));
        #pragma unroll
        for (int o = 32; o > 0; o >>= 1) m = fmaxf(m, __shfl_xor(m, o));
        float sum = __builtin_amdgcn_exp2f(s0 - m) + __builtin_amdgcn_exp2f(s1 - m)
                  + __builtin_amdgcn_exp2f(s2 - m) + __builtin_amdgcn_exp2f(s3 - m);
        #pragma unroll
        for (int o = 32; o > 0; o >>= 1) sum += __shfl_xor(sum, o);
        if (lane == 0) sres[1] = (m + __builtin_amdgcn_logf(sum)) * LN2;
    }
    __syncthreads();
    if (tid == 0) out[b] = sres[0] - sres[1];
}

extern "C" void kernel_launch(void* const* d_in, const int* in_sizes, int n_in,
                              void* d_out, int out_size, void* d_ws, size_t ws_size,
                              hipStream_t stream) {
    (void)in_sizes; (void)n_in; (void)out_size; (void)ws_size;
    const float* xin    = (const float*)d_in[0];
    const int*   target = (const int*)  d_in[1];
    const int*   tsz    = (const int*)  d_in[2];
    const float* trans  = (const float*)d_in[3];
    float* out = (float*)d_out;

    float*          ws_c = (float*)d_ws;                                    // 16 KB
    unsigned short* ws_R = (unsigned short*)((char*)d_ws + 16384);          // 33.55 MB
    float*          ws_v = (float*)((char*)d_ws + 16384 + 33554432);        // 128 KB
    float*          ws_w = (float*)((char*)d_ws + 16384 + 33554432 + 131072);

    // blocks 0..255: wave0 fac (1/CU) + 3 chunk waves; blocks 256..1087: 4 chunk waves
    asg_k1<<<dim3(1088), dim3(256), 0, stream>>>(xin, target, tsz, trans,
                                                 ws_c, ws_R, ws_v, ws_w);
    asg_k2<<<dim3(B_), dim3(128), 0, stream>>>(xin, ws_c, ws_R, ws_v, ws_w, out);
}

// Round 8
// 350.732 us; speedup vs baseline: 1.0269x; 1.0269x over previous
//
#include <hip/hip_runtime.h>

#define B_ 128
#define T_ 2048
#define N_ 64
#define L_ 256
#define NCH 32       // chunks per batch (64 steps each — proven numerics)
#define NEGV (-1e30f)
#define PITCH 72     // shorts per LDS row (64 + 8 pad), keeps b128 16B-aligned
#define LOG2E 1.4426950408889634f
#define LN2   0.6931471805599453f

typedef short  s16x4 __attribute__((ext_vector_type(4)));
typedef short  s16x8 __attribute__((ext_vector_type(8)));
typedef float  f32x4 __attribute__((ext_vector_type(4)));
typedef unsigned int u32x2 __attribute__((ext_vector_type(2)));

__device__ __forceinline__ short f2bf_rne(float f) {
    unsigned u = __float_as_uint(f);
    unsigned r = (u + 0x7FFFu + ((u >> 16) & 1u)) >> 16;
    return (short)r;
}
__device__ __forceinline__ float bf2f(unsigned short u) {
    return __uint_as_float(((unsigned)u) << 16);
}
// pack 2 floats -> 2 bf16 (round-half-up) in one u32 via v_perm_b32
__device__ __forceinline__ unsigned pkpair(float lo, float hi) {
    return __builtin_amdgcn_perm(__float_as_uint(hi) + 0x8000u,
                                 __float_as_uint(lo) + 0x8000u, 0x07060302u);
}
__device__ __forceinline__ float bperm(int byteaddr, float v) {
    return __int_as_float(__builtin_amdgcn_ds_bpermute(byteaddr, __float_as_int(v)));
}
// logaddexp in log2 domain (v_exp_f32/v_log_f32 are base-2)
__device__ __forceinline__ float lse2b(float p, float q) {
    float mx = fmaxf(p, q);
    float t  = __builtin_amdgcn_exp2f(-fabsf(p - q));
    return mx + __builtin_amdgcn_logf(1.f + t);
}

// Kernel 1: blocks 0..31 fwd fac, 32..63 bwd fac (concentrated — measured best),
// blocks 64..575: chunk waves, each builds TWO sequential 64-step chunk matrices.
// 576 blocks -> all co-resident, no straggler round.
__global__ __launch_bounds__(256, 2) void asg_k1(
    const float* __restrict__ x,       // (B,T,N)
    const int*   __restrict__ target,  // (B,L)
    const int*   __restrict__ tsize,   // (B,)
    const float* __restrict__ trans,   // (N,N)
    float* __restrict__ ws_c,          // (B,32) chunk log-scales
    unsigned short* __restrict__ ws_R, // (B,32,64,64) bf16 chunk matrices [m][n]
    float* __restrict__ ws_v,          // (B,256) alpha_1023 (log2 domain)
    float* __restrict__ ws_w)          // (B,256) beta_1023  (log2 domain)
{
    __shared__ short lds[4][N_ * PITCH];
    const int wid  = threadIdx.x >> 6;
    const int lane = threadIdx.x & 63;
    const int W    = blockIdx.x * 4 + wid;

    if (W < 128) {
        // ---------------- FAC forward: alpha_0 .. alpha_1023 ----------------
        const int b  = W;
        const float* __restrict__ xb = x + (size_t)b * T_ * N_;
        const int l0 = lane * 4;
        int tga[4]; float slf[4], mv[4], a[4];
        #pragma unroll
        for (int j = 0; j < 4; ++j) {
            const int tv = target[b * L_ + l0 + j];
            tga[j] = tv << 2;
            slf[j] = trans[tv * N_ + tv] * LOG2E;
            if (j > 0) mv[j] = trans[tv * N_ + (target[b * L_ + l0 + j - 1])] * LOG2E;
            a[j] = NEGV;
        }
        const int tR  = target[b * L_ + ((l0 - 1 >= 0) ? l0 - 1 : 0)];
        const int tR1 = target[b * L_ + ((l0 - 2 >= 0) ? l0 - 2 : 0)];
        const int tgR = tR << 2;
        const float slfR = trans[tR * N_ + tR] * LOG2E;
        const float mvR  = trans[tR * N_ + tR1] * LOG2E;
        mv[0] = trans[(tga[0] >> 2) * N_ + tR] * LOG2E;
        if (lane == 0) a[0] = xb[tga[0] >> 2] * LOG2E;   // alpha0[0]
        float red = NEGV;
        const int upA = ((lane == 0) ? 0 : lane - 1) << 2;

        float xr[16];
        #pragma unroll
        for (int i = 0; i < 16; ++i) xr[i] = xb[(size_t)(1 + i) * N_ + lane];
        float sc = xr[0] * LOG2E;
        float eR = bperm(tgR, sc);
        float e0 = bperm(tga[0], sc), e1 = bperm(tga[1], sc),
              e2 = bperm(tga[2], sc), e3 = bperm(tga[3], sc);
        float bp = bperm(upA, a[2]);

        #define FWD_STEP(i, rp, RF)                                             \
        {                                                                       \
            const float ceR = eR, c0 = e0, c1 = e1, c2 = e2, c3 = e3;           \
            float scn = xr[((i) + 1) & 15] * LOG2E;                             \
            eR = bperm(tgR, scn);                                               \
            e0 = bperm(tga[0], scn); e1 = bperm(tga[1], scn);                   \
            e2 = bperm(tga[2], scn); e3 = bperm(tga[3], scn);                   \
            if (RF) xr[i] = (rp)[lane];                                         \
            const float n0 = lse2b(a[0] + slf[0], red  + mv[0]) + c0;           \
            const float n1 = lse2b(a[1] + slf[1], a[0] + mv[1]) + c1;           \
            const float n2 = lse2b(a[2] + slf[2], a[1] + mv[2]) + c2;           \
            const float n3 = lse2b(a[3] + slf[3], a[2] + mv[3]) + c3;           \
            const float nr = lse2b(red + slfR,    bp   + mvR)   + ceR;          \
            bp = bperm(upA, n2);                                                \
            a[0] = n0; a[1] = n1; a[2] = n2; a[3] = n3;                         \
            red = (lane == 0) ? NEGV : nr;                                      \
        }
        for (int u = 0; u < 63; ++u) {                  // t = 1..1008
            const float* __restrict__ xp = xb + (size_t)(16 * u + 17) * N_;
            #pragma unroll
            for (int i = 0; i < 16; ++i) FWD_STEP(i, xp + i * N_, true);
        }
        #pragma unroll
        for (int i = 0; i < 15; ++i) FWD_STEP(i, xb, false);   // t = 1009..1023
        #undef FWD_STEP
        *(float4*)(ws_v + b * 256 + l0) = make_float4(a[0], a[1], a[2], a[3]);
    } else if (W < 256) {
        // ---------------- FAC backward: beta_2047 .. beta_1023 ----------------
        const int b  = W - 128;
        const float* __restrict__ xb = x + (size_t)b * T_ * N_;
        const int l0 = lane * 4;
        const int lt = tsize[b] - 1;
        int tga[4]; float slf[4], mvin[4], a[4];
        #pragma unroll
        for (int j = 0; j < 4; ++j) {
            const int tv = target[b * L_ + l0 + j];
            tga[j] = tv << 2;
            slf[j] = trans[tv * N_ + tv] * LOG2E;
            if (j > 0) mvin[j] = trans[tv * N_ + (target[b * L_ + l0 + j - 1])] * LOG2E;
            a[j] = (l0 + j == lt) ? 0.f : NEGV;
        }
        const int tR  = target[b * L_ + ((l0 + 4 <= L_ - 1) ? l0 + 4 : L_ - 1)];
        const int tR2 = target[b * L_ + ((l0 + 5 <= L_ - 1) ? l0 + 5 : L_ - 1)];
        const int tgR = tR << 2, tgR2 = tR2 << 2;
        const float slfR = trans[tR * N_ + tR] * LOG2E;
        const float mvR  = trans[tR * N_ + (tga[3] >> 2)] * LOG2E;  // move into 4m+4
        const float mvR2 = trans[tR2 * N_ + tR] * LOG2E;            // move into 4m+5
        float red = (l0 + 4 == lt) ? 0.f : NEGV;
        const int dnA = ((lane == 63) ? 63 : lane + 1) << 2;

        float xr[16];
        #pragma unroll
        for (int i = 0; i < 16; ++i) xr[i] = xb[(size_t)(2047 - i) * N_ + lane];
        float sc = xr[0] * LOG2E;
        float eR = bperm(tgR, sc), eR2 = bperm(tgR2, sc);
        float e0 = bperm(tga[0], sc), e1 = bperm(tga[1], sc),
              e2 = bperm(tga[2], sc), e3 = bperm(tga[3], sc);
        float bp = bperm(dnA, a[1]);

        #define BWD_STEP(i, rp, RF)                                             \
        {                                                                       \
            const float ceR = eR, ceR2 = eR2, c0 = e0, c1 = e1, c2 = e2, c3 = e3;\
            float scn = xr[((i) + 1) & 15] * LOG2E;                             \
            eR = bperm(tgR, scn); eR2 = bperm(tgR2, scn);                       \
            e0 = bperm(tga[0], scn); e1 = bperm(tga[1], scn);                   \
            e2 = bperm(tga[2], scn); e3 = bperm(tga[3], scn);                   \
            if (RF) xr[i] = (rp)[lane];                                         \
            const float t0 = a[0] + c0, t1 = a[1] + c1, t2 = a[2] + c2,         \
                        t3 = a[3] + c3, tr = red + ceR;                         \
            const float n0 = lse2b(t0 + slf[0], t1 + mvin[1]);                  \
            const float n1 = lse2b(t1 + slf[1], t2 + mvin[2]);                  \
            const float n2 = lse2b(t2 + slf[2], t3 + mvin[3]);                  \
            const float n3 = lse2b(t3 + slf[3], tr + mvR);                      \
            const float nr = lse2b(tr + slfR, bp + ceR2 + mvR2);                \
            bp = bperm(dnA, n1);                                                \
            a[0] = n0; a[1] = n1; a[2] = n2; a[3] = n3;                         \
            red = (lane == 63) ? NEGV : nr;                                     \
        }
        for (int u = 0; u < 63; ++u) {                  // t = 2047..1040
            const float* __restrict__ xp = xb + (size_t)(2047 - 16 * u - 16) * N_;
            #pragma unroll
            for (int i = 0; i < 16; ++i) BWD_STEP(i, xp - (size_t)i * N_, true);
        }
        #pragma unroll
        for (int i = 0; i < 16; ++i) BWD_STEP(i, xb, false);   // t = 1039..1024
        #undef BWD_STEP
        *(float4*)(ws_w + b * 256 + l0) = make_float4(a[0], a[1], a[2], a[3]);
    } else {
        // ---- FCC: TWO sequential 64-step chunks per wave (2j, 2j+1) ----
        const int j = W - 256;                    // 0..2047
        const int b = j >> 4, kp = j & 15;
        const int c = lane & 15, g = lane >> 4;
        const float* __restrict__ xb = x + (size_t)b * T_ * N_;
        short* __restrict__ myl = lds[wid];

        // A = Ehat (const across both chunks) + LS
        s16x8 Afrag[4][2];
        float rs[4] = {0.f, 0.f, 0.f, 0.f};
        #pragma unroll
        for (int mt = 0; mt < 4; ++mt)
            #pragma unroll
            for (int kt = 0; kt < 2; ++kt) {
                s16x8 af;
                #pragma unroll
                for (int jj = 0; jj < 8; ++jj) {
                    float v = __expf(trans[(c + 16 * mt) * N_ + 32 * kt + 8 * g + jj]);
                    af[jj] = f2bf_rne(v);
                    rs[mt] += v;
                }
                Afrag[mt][kt] = af;
            }
        #pragma unroll
        for (int mt = 0; mt < 4; ++mt) {
            rs[mt] += __shfl_xor(rs[mt], 16);
            rs[mt] += __shfl_xor(rs[mt], 32);
        }
        float rmax = fmaxf(fmaxf(rs[0], rs[1]), fmaxf(rs[2], rs[3]));
        #pragma unroll
        for (int o = 8; o > 0; o >>= 1) rmax = fmaxf(rmax, __shfl_xor(rmax, o));
        const float LS = __logf(rmax);

        for (int half = 0; half < 2; ++half) {
            const int k  = kp * 2 + half;
            const int t0 = k * 64;

            // B = identity
            s16x8 Bfrag[2][4];
            #pragma unroll
            for (int kt = 0; kt < 2; ++kt)
                #pragma unroll
                for (int nt = 0; nt < 4; ++nt) {
                    s16x8 bf;
                    #pragma unroll
                    for (int jj = 0; jj < 8; ++jj)
                        bf[jj] = (32 * kt + 8 * g + jj == c + 16 * nt) ? (short)0x3F80 : (short)0;
                    Bfrag[kt][nt] = bf;
                }

            float4 xr[2][4];
            #pragma unroll
            for (int p = 0; p < 2; ++p)
                #pragma unroll
                for (int tr = 0; tr < 4; ++tr)
                    xr[p][tr] = *(const float4*)(xb + (size_t)(t0 + 1 + p) * N_ + 16 * tr + 4 * g);

            float c_acc = 0.f;
            #pragma unroll 2
            for (int s = 0; s < 64; ++s) {
                const int t = t0 + 1 + s;
                f32x4 Cacc[4][4];
                #pragma unroll
                for (int mt = 0; mt < 4; ++mt)
                    #pragma unroll
                    for (int nt = 0; nt < 4; ++nt) {
                        f32x4 z = {0.f, 0.f, 0.f, 0.f};
                        z = __builtin_amdgcn_mfma_f32_16x16x32_bf16(Afrag[mt][0], Bfrag[0][nt], z, 0, 0, 0);
                        Cacc[mt][nt] = __builtin_amdgcn_mfma_f32_16x16x32_bf16(Afrag[mt][1], Bfrag[1][nt], z, 0, 0, 0);
                    }
                float4 xv[4];
                #pragma unroll
                for (int tr = 0; tr < 4; ++tr) xv[tr] = xr[s & 1][tr];
                int tpre = t + 2; if (tpre > T_ - 1) tpre = T_ - 1;
                #pragma unroll
                for (int tr = 0; tr < 4; ++tr)
                    xr[s & 1][tr] = *(const float4*)(xb + (size_t)tpre * N_ + 16 * tr + 4 * g);

                const float gt = __uint_as_float(__builtin_amdgcn_readfirstlane(__float_as_uint(xv[0].x))) + LS;
                if (t < T_) {
                    c_acc += gt;
                    float ev[4][4];
                    #pragma unroll
                    for (int tr = 0; tr < 4; ++tr) {
                        ev[tr][0] = __expf(xv[tr].x - gt);
                        ev[tr][1] = __expf(xv[tr].y - gt);
                        ev[tr][2] = __expf(xv[tr].z - gt);
                        ev[tr][3] = __expf(xv[tr].w - gt);
                    }
                    #pragma unroll
                    for (int mt = 0; mt < 4; ++mt)
                        #pragma unroll
                        for (int nt = 0; nt < 4; ++nt) {
                            u32x2 pk;
                            pk[0] = pkpair(Cacc[mt][nt][0] * ev[mt][0], Cacc[mt][nt][1] * ev[mt][1]);
                            pk[1] = pkpair(Cacc[mt][nt][2] * ev[mt][2], Cacc[mt][nt][3] * ev[mt][3]);
                            *(u32x2*)&myl[(16 * nt + c) * PITCH + 16 * mt + 4 * g] = pk;
                        }
                    #pragma unroll
                    for (int kt = 0; kt < 2; ++kt)
                        #pragma unroll
                        for (int nt = 0; nt < 4; ++nt)
                            Bfrag[kt][nt] = *(const s16x8*)&myl[(16 * nt + c) * PITCH + 32 * kt + 8 * g];
                }
            }
            // store transposed [m][n]: dst[i*64+j], coalesced over lanes
            unsigned short* dst = ws_R + (size_t)(b * NCH + k) * 4096;
            #pragma unroll
            for (int r = 0; r < 8; ++r) {
                s16x8 v = *(const s16x8*)&myl[lane * PITCH + r * 8];  // v[e]=P[8r+e][lane]
                #pragma unroll
                for (int e = 0; e < 8; ++e)
                    dst[(8 * r + e) * 64 + lane] = (unsigned short)v[e];
            }
            if (lane == 0) ws_c[b * NCH + k] = c_acc;
        }
    }
}

// Kernel 2: 256 threads/block. All 4 waves cooperatively stage chunk matrices
// into a 4-slot LDS ring (4x in-flight bytes vs 1 wave); wave0 runs the serial
// fcc combine; wave1 additionally does the fac combine. One block per batch.
__global__ __launch_bounds__(256) void asg_k2(
    const float* __restrict__ x,
    const float* __restrict__ ws_c,
    const unsigned short* __restrict__ ws_R,
    const float* __restrict__ ws_v,
    const float* __restrict__ ws_w,
    float* __restrict__ out)
{
    __shared__ short ring[4][N_ * PITCH];
    __shared__ __align__(16) float sa[N_];
    __shared__ float sres[2];
    const int b = blockIdx.x, tid = threadIdx.x;
    const int lane = tid & 63, wv = tid >> 6;
    const unsigned short* Rb = ws_R + (size_t)b * NCH * 4096;

    // stage chunk kc -> ring[kc&3]: 256 lanes x 16 shorts (2 x b128)
    const int srow = tid >> 2, scol = (tid & 3) * 16;
    #define STAGE(kc)                                                       \
    {                                                                       \
        const unsigned short* src = Rb + (size_t)(kc) * 4096 + tid * 16;    \
        s16x8 v0 = *(const s16x8*)(src);                                    \
        s16x8 v1 = *(const s16x8*)(src + 8);                                \
        short* d = &ring[(kc) & 3][srow * PITCH + scol];                    \
        *(s16x8*)d = v0;                                                    \
        *(s16x8*)(d + 8) = v1;                                              \
    }

    if (wv == 1) {
        // fac combine: lse over 256 cells of (alpha+beta), log2 in -> ln out
        float4 v4 = ((const float4*)(ws_v + b * 256))[lane];
        float4 w4 = ((const float4*)(ws_w + b * 256))[lane];
        const float s0 = v4.x + w4.x, s1 = v4.y + w4.y,
                    s2 = v4.z + w4.z, s3 = v4.w + w4.w;
        float m = fmaxf(fmaxf(s0, s1), fmaxf(s2, s3));
        #pragma unroll
        for (int o = 32; o > 0; o >>= 1) m = fmaxf(m, __shfl_xor(m, o));
        float sum = __builtin_amdgcn_exp2f(s0 - m) + __builtin_amdgcn_exp2f(s1 - m)
                  + __builtin_amdgcn_exp2f(s2 - m) + __builtin_amdgcn_exp2f(s3 - m);
        #pragma unroll
        for (int o = 32; o > 0; o >>= 1) sum += __shfl_xor(sum, o);
        if (lane == 0) sres[1] = (m + __builtin_amdgcn_logf(sum)) * LN2;
    }

    STAGE(0); STAGE(1); STAGE(2);

    float a = 0.f; double Cd = 0.0;
    if (wv == 0) {
        float a0 = x[(size_t)b * T_ * N_ + lane];
        float m0 = a0;
        #pragma unroll
        for (int o = 32; o > 0; o >>= 1) m0 = fmaxf(m0, __shfl_xor(m0, o));
        a  = __expf(a0 - m0);
        Cd = (double)m0;
    }
    __syncthreads();

    for (int kk = 0; kk < NCH; ++kk) {
        if (wv == 0) {
            sa[lane] = a;
            float4 sav[16];
            #pragma unroll
            for (int q = 0; q < 16; ++q) sav[q] = ((const float4*)sa)[q];

            float acc4[4] = {0.f, 0.f, 0.f, 0.f};
            #pragma unroll
            for (int u = 0; u < 8; ++u) {
                s16x8 rr = *(const s16x8*)&ring[kk & 3][lane * PITCH + u * 8];
                const float4 s0 = sav[2 * u], s1 = sav[2 * u + 1];
                acc4[0] = fmaf(bf2f((unsigned short)rr[0]), s0.x, acc4[0]);
                acc4[1] = fmaf(bf2f((unsigned short)rr[1]), s0.y, acc4[1]);
                acc4[2] = fmaf(bf2f((unsigned short)rr[2]), s0.z, acc4[2]);
                acc4[3] = fmaf(bf2f((unsigned short)rr[3]), s0.w, acc4[3]);
                acc4[0] = fmaf(bf2f((unsigned short)rr[4]), s1.x, acc4[0]);
                acc4[1] = fmaf(bf2f((unsigned short)rr[5]), s1.y, acc4[1]);
                acc4[2] = fmaf(bf2f((unsigned short)rr[6]), s1.z, acc4[2]);
                acc4[3] = fmaf(bf2f((unsigned short)rr[7]), s1.w, acc4[3]);
            }
            float acc = (acc4[0] + acc4[1]) + (acc4[2] + acc4[3]);
            // cheap renorm: all-positive acc; lane0's value within e^+-15 of max
            float r = bperm(0, acc);
            a = acc * __builtin_amdgcn_rcpf(r);
            Cd += (double)(__logf(r) + ws_c[b * NCH + kk]);
        }
        if (kk + 3 < NCH) STAGE(kk + 3);
        __syncthreads();
    }
    #undef STAGE

    if (wv == 0) {
        float ssum = a;
        #pragma unroll
        for (int o = 32; o > 0; o >>= 1) ssum += __shfl_xor(ssum, o);
        if (lane == 0) sres[0] = (float)(Cd + (double)__logf(ssum));
    }
    __syncthreads();
    if (tid == 0) out[b] = sres[0] - sres[1];
}

extern "C" void kernel_launch(void* const* d_in, const int* in_sizes, int n_in,
                              void* d_out, int out_size, void* d_ws, size_t ws_size,
                              hipStream_t stream) {
    (void)in_sizes; (void)n_in; (void)out_size; (void)ws_size;
    const float* xin    = (const float*)d_in[0];
    const int*   target = (const int*)  d_in[1];
    const int*   tsz    = (const int*)  d_in[2];
    const float* trans  = (const float*)d_in[3];
    float* out = (float*)d_out;

    float*          ws_c = (float*)d_ws;                                    // 16 KB
    unsigned short* ws_R = (unsigned short*)((char*)d_ws + 16384);          // 33.55 MB
    float*          ws_v = (float*)((char*)d_ws + 16384 + 33554432);        // 128 KB
    float*          ws_w = (float*)((char*)d_ws + 16384 + 33554432 + 131072);

    // 64 fac blocks (128 fwd + 128 bwd waves) + 512 chunk blocks (1024 waves x 2 chunks)
    asg_k1<<<dim3(576), dim3(256), 0, stream>>>(xin, target, tsz, trans,
                                                ws_c, ws_R, ws_v, ws_w);
    asg_k2<<<dim3(B_), dim3(256), 0, stream>>>(xin, ws_c, ws_R, ws_v, ws_w, out);
}